// Round 18
// baseline (223.482 us; speedup 1.0000x reference)
//
#include <hip/hip_runtime.h>

typedef __attribute__((ext_vector_type(4))) int i32x4;

#define NB   32
#define HH   112
#define WW   112
#define CIN  128
#define OH_  110
#define OW_  110
#define COUT 256
#define NCHUNK 18                      // 9 taps x 2 K-halves of 64
#define M_TOTAL (NB * OH_ * OW_)       // 387200
#define BM 128
#define GRID_M (M_TOTAL / BM)          // 3025 exactly, no tail

// Binarize weights -> int8 {-1,+1}, packed per (chunk, n-half) in fragment order:
// 16B slot = ((chunk*2 + nh)*8 + nb)*64 + lane  (16 KB per chunk, full N=256).
// byte j: n = nh*128 + nb*16 + (lane&15); ci = (chunk&1)*64 + (lane>>4)*16 + j;
// tap = chunk>>1. kern is [tap][ci][n].
__global__ void prep_weights(const float* __restrict__ kern, char* __restrict__ bq) {
  int idx = blockIdx.x * 256 + threadIdx.x;   // 18*2*8*64 = 18432
  if (idx >= NCHUNK * 2 * 8 * 64) return;
  int lane  = idx & 63;
  int nb    = (idx >> 6) & 7;
  int nh    = (idx >> 9) & 1;
  int chunk = idx >> 10;
  int tap   = chunk >> 1;
  int n     = nh * 128 + nb * 16 + (lane & 15);
  int cib   = (chunk & 1) * 64 + ((lane >> 4) << 4);
  int w[4] = {0, 0, 0, 0};
#pragma unroll
  for (int j = 0; j < 16; ++j) {
    float kv = kern[(tap * CIN + cib + j) * COUT + n];
    float hs = fminf(fmaxf((kv + 1.0f) * 0.5f, 0.0f), 1.0f);
    int b = (rintf(hs) > 0.5f) ? 1 : -1;   // round-half-even like jnp.round
    w[j >> 2] |= (b & 255) << ((j & 3) * 8);
  }
  *(i32x4*)(bq + (long)idx * 16) = (i32x4){w[0], w[1], w[2], w[3]};
}

__device__ __forceinline__ void gload16(const char* g, char* l) {
  __builtin_amdgcn_global_load_lds(
      (const __attribute__((address_space(1))) unsigned int*)g,
      (__attribute__((address_space(3))) unsigned int*)l, 16, 0, 0);
}

// round-half-even int8 quantize via magic-number (single fma; exact RNE at 2^23)
__device__ __forceinline__ int q8(float v) {
  float t = fminf(fmaxf(v, -6.f), 6.f);
  float f = fmaf(t, 127.f / 6.f, 12582912.f);   // 1.5 * 2^23
  return __float_as_int(f) & 0xFF;               // 0x400000 % 256 == 0
}

#define BAR()   __builtin_amdgcn_s_barrier()
#define LGKM0() asm volatile("s_waitcnt lgkmcnt(0)" ::: "memory")

// ==== int8, BM=128 x BN=256, 512 thr (2m x 4n waves of 64x64);
// A staged from fp32 x with FUSED in-register quantize (reg->cvt->ds_write),
// B 3-ring gload_lds (48 KB); 64 KB LDS -> 2 blocks/CU; NT stores. ===========
__global__ __launch_bounds__(512, 4) void bconv(
    const float* __restrict__ x, const char* __restrict__ bq,
    const float* __restrict__ bias, float* __restrict__ out) {
  extern __shared__ char lds[];
  // A slots: 0, 8192 (128 rows x 64 B int8, kq-XOR-swizzled content)
  // B slots: 16384, 32768, 49152 (16 KB each, fragment-linear, full N=256)

  const int tid  = threadIdx.x;
  const int lane = tid & 63;
  const int wave = tid >> 6;
  const int wm   = wave >> 2;   // 0..1 (64-row half)
  const int wn   = wave & 3;    // 0..3 (64-col band)

  // bijective XCD-chunked swizzle (m204) over 3025 M-blocks
  const int q = GRID_M >> 3, r = GRID_M & 7;
  const int xcd = (int)blockIdx.x & 7, ob = (int)blockIdx.x >> 3;
  const int bid = (xcd < r ? xcd * (q + 1) : r * (q + 1) + (xcd - r) * q) + ob;
  const long m0 = (long)bid * BM;

  // ---- A staging: thread covers row tid>>2, source quarter tid&3 (16 floats,
  //      contiguous). ds_write goes to slot (tid&3)^(row&3) -> read-side XOR ok.
  const int wrow = tid >> 2;
  long rbasef;
  {
    long mrow = m0 + wrow;                        // < M_TOTAL (exact tiling)
    int nimg = (int)(mrow / (OH_ * OW_));
    int r2   = (int)(mrow - (long)nimg * (OH_ * OW_));
    int oh   = r2 / OW_;
    int ow   = r2 - oh * OW_;
    rbasef = (((long)nimg * HH + oh) * WW + ow) * CIN + (tid & 3) * 16;
  }
  const int awr = wrow * 64 + (((tid & 3) ^ (wrow & 3)) << 4);  // ds_write addr

#define A_LOAD(av, cN) do {                                                  \
    const int t_ = (cN) >> 1;                                                \
    const float* xp_ = x + rbasef + (long)((t_ / 3) * WW + (t_ % 3)) * CIN   \
                         + ((cN) & 1) * 64;                                  \
    (av)[0] = *(const float4*)(xp_);                                         \
    (av)[1] = *(const float4*)(xp_ + 4);                                     \
    (av)[2] = *(const float4*)(xp_ + 8);                                     \
    (av)[3] = *(const float4*)(xp_ + 12);                                    \
  } while (0)

#define A_WRITE(av, aoff) do {                                               \
    i32x4 w_;                                                                \
    _Pragma("unroll")                                                        \
    for (int k_ = 0; k_ < 4; ++k_)                                           \
      w_[k_] = q8((av)[k_].x) | (q8((av)[k_].y) << 8) |                      \
               (q8((av)[k_].z) << 16) | (q8((av)[k_].w) << 24);              \
    *(i32x4*)(lds + (aoff) + awr) = w_;                                      \
  } while (0)

#define STAGE_B(boff, cN) do {                                               \
    const char* bs_ = bq + (long)(cN) * 16384 + tid * 16;                    \
    gload16(bs_,        lds + (boff) + tid * 16);                            \
    gload16(bs_ + 8192, lds + (boff) + tid * 16 + 8192);                     \
  } while (0)

  // ---- fragment read addressing ----
  // A: row = wm*64 + mi*16 + (lane&15); addr = row*64 + ((lane>>4)^(row&3))*16;
  //    row&3 == lane&3 -> constant per thread.
  const int arow = (wm * 64 + (lane & 15)) * 64;    // + mi*1024 + kqrd
  const int kqrd = (((lane >> 4) ^ (lane & 3)) << 4);
  const int brd  = (wn * 4) * 1024 + lane * 16;     // + ni*1024

  i32x4 acc[4][4];
#pragma unroll
  for (int i = 0; i < 4; ++i)
#pragma unroll
    for (int j = 0; j < 4; ++j) acc[i][j] = (i32x4){0, 0, 0, 0};

  float4 av[4];
  // ---- prologue: A(0) load+cvt+write; B(0),B(1) gloads; drain B(0) ----
  A_LOAD(av, 0);
  STAGE_B(16384, 0);
  STAGE_B(32768, 1);
  A_WRITE(av, 0);            // compiler waits the 4 A-loads (vmcnt<=4)
  LGKM0();
  asm volatile("s_waitcnt vmcnt(2)" ::: "memory");   // B(0) landed
  BAR();

  int a0 = 0, a1 = 8192;
  int b0 = 16384, b1 = 32768, b2 = 49152;
#pragma unroll 1
  for (int c = 0; c < NCHUNK; ++c) {
    // issue A(c+1) fp32 loads early (latency hides under MFMA below)
    if (c + 1 < NCHUNK) A_LOAD(av, c + 1);
    if (c + 2 < NCHUNK) STAGE_B(b2, c + 2);

    i32x4 af[4], bf[4];
#pragma unroll
    for (int mi = 0; mi < 4; ++mi)
      af[mi] = *(const i32x4*)(lds + a0 + arow + mi * 1024 + kqrd);
#pragma unroll
    for (int ni = 0; ni < 4; ++ni)
      bf[ni] = *(const i32x4*)(lds + b0 + brd + ni * 1024);
#pragma unroll
    for (int mi = 0; mi < 4; ++mi)
#pragma unroll
      for (int ni = 0; ni < 4; ++ni)
        acc[mi][ni] = __builtin_amdgcn_mfma_i32_16x16x64_i8(af[mi], bf[ni], acc[mi][ni], 0, 0, 0);

    // cvt+write A(c+1): compiler's wait for av (FIFO) also retires the older
    // B(c+1) gloads -> boundary needs only lgkm drain + barrier.
    if (c + 1 < NCHUNK) {
      A_WRITE(av, a1);
      LGKM0();
      BAR();
      int t = a0; a0 = a1; a1 = t;
      int u = b0; b0 = b1; b1 = b2; b2 = u;
    }
  }
#undef A_LOAD
#undef A_WRITE
#undef STAGE_B

  // ---- Epilogue: NT stores (output never re-read; keep L2/L3 for x/bq) ----
  const float S = 6.f / 127.f;
  const int  colb = wn * 64 + (lane & 15);
  const long rowb = m0 + wm * 64 + ((lane >> 4) << 2);
#pragma unroll
  for (int ni = 0; ni < 4; ++ni) {
    const int col = colb + ni * 16;
    const float bv = bias[col];
#pragma unroll
    for (int mi = 0; mi < 4; ++mi)
#pragma unroll
      for (int rr = 0; rr < 4; ++rr)
        __builtin_nontemporal_store((float)acc[mi][ni][rr] * S + bv,
                                    &out[(rowb + mi * 16 + rr) * COUT + col]);
  }
}

extern "C" void kernel_launch(void* const* d_in, const int* in_sizes, int n_in,
                              void* d_out, int out_size, void* d_ws, size_t ws_size,
                              hipStream_t stream) {
  const float* x    = (const float*)d_in[0];
  const float* kern = (const float*)d_in[1];
  const float* bias = (const float*)d_in[2];
  float* out = (float*)d_out;

  char* bq = (char*)d_ws;   // 294912 B

  (void)hipFuncSetAttribute((const void*)bconv,
                            hipFuncAttributeMaxDynamicSharedMemorySize, 65536);

  prep_weights<<<dim3(72), dim3(256), 0, stream>>>(kern, bq);
  bconv<<<dim3(GRID_M), dim3(512), 65536, stream>>>(x, bq, bias, out);
}